// Round 1
// 196.227 us; speedup vs baseline: 1.0825x; 1.0825x over previous
//
#include <hip/hip_runtime.h>
#include <hip/hip_bf16.h>

// Problem constants
#define BB 4
#define LL 1024
#define DD 1024
#define HH 16
#define DHH 64
#define DTT 100
#define ML (BB*LL)          // 4096 rows
#define LOG2E 1.4426950408889634f

typedef float f32x4 __attribute__((ext_vector_type(4)));
typedef short s16x8 __attribute__((ext_vector_type(8)));

__device__ __forceinline__ unsigned short f2bf(float x) {
    unsigned u = __builtin_bit_cast(unsigned, x);
    return (unsigned short)((u + 0x7FFFu + ((u >> 16) & 1u)) >> 16);   // RNE
}
__device__ __forceinline__ unsigned short f2bf_fast(float x) {
    return (unsigned short)((__builtin_bit_cast(unsigned, x) + 0x8000u) >> 16);  // round-half-up
}
__device__ __forceinline__ unsigned cvt_pk_bf16(float lo, float hi) {
    unsigned r;
    asm("v_cvt_pk_bf16_f32 %0, %1, %2" : "=v"(r) : "v"(lo), "v"(hi));
    return r;   // [bf16(lo) | bf16(hi)<<16]
}
__device__ __forceinline__ float bflo(unsigned u) { return __builtin_bit_cast(float, u << 16); }
__device__ __forceinline__ float bfhi(unsigned u) { return __builtin_bit_cast(float, u & 0xFFFF0000u); }
__device__ __forceinline__ int4 pack_bf16x8(float4 x0, float4 x1) {
    int4 o;
    o.x = cvt_pk_bf16(x0.x, x0.y); o.y = cvt_pk_bf16(x0.z, x0.w);
    o.z = cvt_pk_bf16(x1.x, x1.y); o.w = cvt_pk_bf16(x1.z, x1.w);
    return o;
}

// ---------------------------------------------------------------------------
// Fused converts + mask pack in ONE launch (segmented grid, exact counts)
// ---------------------------------------------------------------------------
__global__ __launch_bounds__(256)
void conv_fused(const float* __restrict__ w0, const float* __restrict__ w1,
                const float* __restrict__ w2, const float* __restrict__ w3,
                const float* __restrict__ w4, unsigned short* __restrict__ wd,
                const float* __restrict__ wtw, unsigned short* __restrict__ wtwd,
                const float* __restrict__ wtv, unsigned short* __restrict__ wtvd,
                const float* __restrict__ topic, unsigned short* __restrict__ topicd,
                const int* __restrict__ mask, unsigned long long* __restrict__ MB) {
    const int bx = blockIdx.x, tid = threadIdx.x;
    if (bx < 2560) {
        const int which = bx >> 9;
        const float* src;
        switch (which) {
            case 0:  src = w0; break;
            case 1:  src = w1; break;
            case 2:  src = w2; break;
            case 3:  src = w3; break;
            default: src = w4; break;
        }
        unsigned short* dst = wd + (size_t)which * DD * DD;
        const int idx = (bx & 511) * 256 + tid;
        float4 f0 = *(const float4*)(src + (size_t)idx * 8);
        float4 f1 = *(const float4*)(src + (size_t)idx * 8 + 4);
        *(int4*)(dst + (size_t)idx * 8) = pack_bf16x8(f0, f1);
    } else if (bx < 2584) {
        const int idx = (bx - 2560) * 256 + tid;
        float4 f0 = *(const float4*)(wtw + (size_t)idx * 8);
        float4 f1 = *(const float4*)(wtw + (size_t)idx * 8 + 4);
        *(int4*)(wtwd + (size_t)idx * 8) = pack_bf16x8(f0, f1);
    } else if (bx < 2648) {
        const int idx = (bx - 2584) * 256 + tid;
        const int r = idx >> 4, c0 = (idx & 15) * 8;
        unsigned short o[8];
        #pragma unroll
        for (int j = 0; j < 8; j++) {
            int c = c0 + j;
            o[j] = (c < DTT) ? f2bf(wtv[(size_t)r * DTT + c]) : (unsigned short)0;
        }
        int4 v;
        v.x = o[0] | ((unsigned)o[1] << 16);
        v.y = o[2] | ((unsigned)o[3] << 16);
        v.z = o[4] | ((unsigned)o[5] << 16);
        v.w = o[6] | ((unsigned)o[7] << 16);
        *(int4*)(wtvd + (size_t)r * 128 + c0) = v;
    } else if (bx < 2904) {
        const int idx = (bx - 2648) * 256 + tid;
        const int r = idx >> 4, c0 = (idx & 15) * 8;
        unsigned short o[8];
        #pragma unroll
        for (int j = 0; j < 8; j++) {
            int c = c0 + j;
            o[j] = (c < DTT) ? f2bf(topic[(size_t)r * DTT + c]) : (unsigned short)0;
        }
        int4 v;
        v.x = o[0] | ((unsigned)o[1] << 16);
        v.y = o[2] | ((unsigned)o[3] << 16);
        v.z = o[4] | ((unsigned)o[5] << 16);
        v.w = o[6] | ((unsigned)o[7] << 16);
        *(int4*)(topicd + (size_t)r * 128 + c0) = v;
    } else {
        const int ww = (bx - 2904) * 4 + (tid >> 6);
        const int lane = tid & 63;
        int v = mask[(size_t)ww * 64 + lane];
        unsigned long long bits = __ballot(v != 0);
        if (lane == 0) MB[ww] = bits;
    }
}

// ---------------------------------------------------------------------------
// bf16 MFMA GEMM, XCD-swizzled, r9 1-DEEP NAMED-SCALAR REG PREFETCH for
// BOTH paths, 32KB LDS, __launch_bounds__(256,3) -> 3 blocks/CU.
// mode: 0 fp32 C; 1 bf16 C; 2/3 KC halves; 4 VT transposed.
// ---------------------------------------------------------------------------
struct GArg { const void* A; const unsigned short* W; const float* bias; void* C; int mode; };

#define LOADW(s0_,s1_,s2_,s3_,kk) \
    s0_ = *(const int4*)(Wb + (kk)); \
    s1_ = *(const int4*)(Wb + (kk) + wstep); \
    s2_ = *(const int4*)(Wb + (kk) + 2 * wstep); \
    s3_ = *(const int4*)(Wb + (kk) + 3 * wstep);
#define STOREW(s0_,s1_,s2_,s3_) \
    *(int4*)(bsl)         = s0_; \
    *(int4*)(bsl + 4096)  = s1_; \
    *(int4*)(bsl + 8192)  = s2_; \
    *(int4*)(bsl + 12288) = s3_;
#define LOADA16(s0_,s1_,s2_,s3_,kk) \
    s0_ = *(const int4*)(Ab16 + (kk)); \
    s1_ = *(const int4*)(Ab16 + (kk) + wstep); \
    s2_ = *(const int4*)(Ab16 + (kk) + 2 * wstep); \
    s3_ = *(const int4*)(Ab16 + (kk) + 3 * wstep);
#define STOREA16(s0_,s1_,s2_,s3_) \
    *(int4*)(asl)         = s0_; \
    *(int4*)(asl + 4096)  = s1_; \
    *(int4*)(asl + 8192)  = s2_; \
    *(int4*)(asl + 12288) = s3_;
#define LOADA32(q0_,q1_,q2_,q3_,q4_,q5_,q6_,q7_,kk) \
    q0_ = *(const float4*)(Af32 + (kk));             q1_ = *(const float4*)(Af32 + (kk) + 4); \
    q2_ = *(const float4*)(Af32 + (kk) + wstep);     q3_ = *(const float4*)(Af32 + (kk) + wstep + 4); \
    q4_ = *(const float4*)(Af32 + (kk) + 2 * wstep); q5_ = *(const float4*)(Af32 + (kk) + 2 * wstep + 4); \
    q6_ = *(const float4*)(Af32 + (kk) + 3 * wstep); q7_ = *(const float4*)(Af32 + (kk) + 3 * wstep + 4);
#define STOREA32(q0_,q1_,q2_,q3_,q4_,q5_,q6_,q7_) \
    *(int4*)(asl)         = pack_bf16x8(q0_, q1_); \
    *(int4*)(asl + 4096)  = pack_bf16x8(q2_, q3_); \
    *(int4*)(asl + 8192)  = pack_bf16x8(q4_, q5_); \
    *(int4*)(asl + 12288) = pack_bf16x8(q6_, q7_);
#define GEMM_COMPUTE(ABASE, BBASE) \
    _Pragma("unroll") \
    for (int ks = 0; ks < 2; ks++) { \
        s16x8 af[4], bf[4]; \
        _Pragma("unroll") \
        for (int m = 0; m < 4; m++) { \
            const int ra = wr * 64 + m * 16 + c; \
            af[m] = *(const s16x8*)((ABASE) + ra * 128 + (((ks * 4 + g) ^ (ra & 7)) << 4)); \
            const int rb = wc * 64 + m * 16 + c; \
            bf[m] = *(const s16x8*)((BBASE) + rb * 128 + (((ks * 4 + g) ^ (rb & 7)) << 4)); \
        } \
        _Pragma("unroll") \
        for (int m = 0; m < 4; m++) \
            _Pragma("unroll") \
            for (int n = 0; n < 4; n++) \
                acc[m][n] = __builtin_amdgcn_mfma_f32_16x16x32_bf16(af[m], bf[n], acc[m][n], 0, 0, 0); \
    }

template<int AFP32>
__global__ __launch_bounds__(256, 3)
void gemm_mfma(GArg a0, GArg a1, GArg a2, GArg a3, int N, int K) {
    __shared__ char lds[32768];
    char* As = lds;
    char* Bs = lds + 16384;

    // ---- XCD-aware block remap (grids here are always multiples of 8)
    const int nb = gridDim.x * gridDim.y * gridDim.z;
    const int flat = blockIdx.x + gridDim.x * (blockIdx.y + gridDim.y * blockIdx.z);
    const int wid = (flat & 7) * (nb >> 3) + (flat >> 3);
    const int bx = wid % gridDim.x;
    const int rem = wid / gridDim.x;
    const int by = rem % gridDim.y;
    const int bz = rem / gridDim.y;

    GArg a;
    switch (bz) {
        case 0:  a = a0; break;
        case 1:  a = a1; break;
        case 2:  a = a2; break;
        default: a = a3; break;
    }

    const int tid = threadIdx.x, w = tid >> 6, l = tid & 63;
    const int g = l >> 4, c = l & 15;
    const int wr = w >> 1, wc = w & 1;
    const int bm = by * 128, bn = bx * 128;

    const int r0 = tid >> 3, sl = tid & 7;
    char* const asl = As + r0 * 128 + ((sl ^ (r0 & 7)) << 4);
    char* const bsl = Bs + r0 * 128 + ((sl ^ (r0 & 7)) << 4);
    const size_t wstep = (size_t)32 * K;
    const unsigned short* const Wb   = a.W + (size_t)(bn + r0) * K + sl * 8;
    const unsigned short* const Ab16 = (const unsigned short*)a.A + (size_t)(bm + r0) * K + sl * 8;
    const float* const           Af32 = (const float*)a.A + (size_t)(bm + r0) * K + sl * 8;

    f32x4 acc[4][4];
    #pragma unroll
    for (int m = 0; m < 4; m++)
        #pragma unroll
        for (int n = 0; n < 4; n++)
            #pragma unroll
            for (int j = 0; j < 4; j++) acc[m][n][j] = 0.f;

    // ---- prologue: 1-deep prefetch of K-step 0 into named registers
    int4 pw0, pw1, pw2, pw3;
    int4 pa0, pa1, pa2, pa3;                       // bf16-A path
    float4 qa0, qa1, qa2, qa3, qa4, qa5, qa6, qa7; // fp32-A path (raw)
    LOADW(pw0, pw1, pw2, pw3, 0)
    if (AFP32) { LOADA32(qa0, qa1, qa2, qa3, qa4, qa5, qa6, qa7, 0) }
    else       { LOADA16(pa0, pa1, pa2, pa3, 0) }

    for (int k0 = 0; k0 < K; k0 += 64) {
        __syncthreads();   // readers of previous tile done
        if (AFP32) { STOREA32(qa0, qa1, qa2, qa3, qa4, qa5, qa6, qa7) }
        else       { STOREA16(pa0, pa1, pa2, pa3) }
        STOREW(pw0, pw1, pw2, pw3)
        {
            const int kn = (k0 + 64 < K) ? (k0 + 64) : 0;   // clamp in-bounds
            LOADW(pw0, pw1, pw2, pw3, kn)
            if (AFP32) { LOADA32(qa0, qa1, qa2, qa3, qa4, qa5, qa6, qa7, kn) }
            else       { LOADA16(pa0, pa1, pa2, pa3, kn) }
        }
        __syncthreads();   // staging visible
        GEMM_COMPUTE(As, Bs)
    }

    const int mode = a.mode;
    if (mode == 0) {
        float* C = (float*)a.C;
        #pragma unroll
        for (int n = 0; n < 4; n++) {
            const int col = bn + wc * 64 + n * 16 + c;
            const float bv = a.bias[col];
            #pragma unroll
            for (int m = 0; m < 4; m++) {
                const int row = bm + wr * 64 + m * 16 + g * 4;
                #pragma unroll
                for (int j = 0; j < 4; j++)
                    C[(size_t)(row + j) * N + col] = acc[m][n][j] + bv;
            }
        }
    } else if (mode == 1) {
        unsigned short* C = (unsigned short*)a.C;
        #pragma unroll
        for (int n = 0; n < 4; n++) {
            const int col = bn + wc * 64 + n * 16 + c;
            const float bv = a.bias[col];
            #pragma unroll
            for (int m = 0; m < 4; m++) {
                const int row = bm + wr * 64 + m * 16 + g * 4;
                #pragma unroll
                for (int j = 0; j < 4; j++)
                    C[(size_t)(row + j) * N + col] = f2bf(acc[m][n][j] + bv);
            }
        }
    } else if (mode == 2 || mode == 3) {
        unsigned short* C = (unsigned short*)a.C;
        const int off = (mode == 2) ? 0 : 64;
        #pragma unroll
        for (int n = 0; n < 4; n++) {
            const int col = bn + wc * 64 + n * 16 + c;
            const float bv = a.bias[col];
            const int h = col >> 6, d = col & 63;
            #pragma unroll
            for (int m = 0; m < 4; m++) {
                const int row = bm + wr * 64 + m * 16 + g * 4;
                #pragma unroll
                for (int j = 0; j < 4; j++) {
                    const int rr = row + j;
                    C[((size_t)((rr >> 10) * HH + h) * LL + (rr & 1023)) * 128 + off + d] =
                        f2bf(acc[m][n][j] + bv);
                }
            }
        }
    } else {   // mode 4: VT[(b*16+h)][d][l], pack 4 consecutive l
        unsigned short* C = (unsigned short*)a.C;
        #pragma unroll
        for (int n = 0; n < 4; n++) {
            const int col = bn + wc * 64 + n * 16 + c;
            const float bv = a.bias[col];
            const int h = col >> 6, d = col & 63;
            #pragma unroll
            for (int m = 0; m < 4; m++) {
                const int row = bm + wr * 64 + m * 16 + g * 4;
                unsigned lo = cvt_pk_bf16(acc[m][n][0] + bv, acc[m][n][1] + bv);
                unsigned hi = cvt_pk_bf16(acc[m][n][2] + bv, acc[m][n][3] + bv);
                unsigned long long pk = (unsigned long long)lo | ((unsigned long long)hi << 32);
                *(unsigned long long*)(C + ((size_t)((row >> 10) * HH + h) * 64 + d) * LL + (row & 1023)) = pk;
            }
        }
    }
}

// ---------------------------------------------------------------------------
// Gate: gate[row,h] = sigmoid( Wtw[h] . [q_lin|tk_lin|tv_lin](row) + btw[h] )
// ---------------------------------------------------------------------------
__global__ __launch_bounds__(256)
void gate_kernel(const unsigned short* __restrict__ QLb,
                 const unsigned short* __restrict__ KCb,
                 const unsigned short* __restrict__ TVLb,
                 const unsigned short* __restrict__ Wtwb,
                 const float* __restrict__ btw, float* __restrict__ GATE) {
    const int t = threadIdx.x;
    const int q = t >> 6, sub = t & 63, row = sub >> 4, h = sub & 15;
    const int row_g = blockIdx.x * 4 + row;
    const int b = row_g >> 10, l = row_g & 1023;

    float acc = 0.f;
    const unsigned short* wp = Wtwb + h * 3 * DD + q * 768;
    #pragma unroll 4
    for (int cc = 0; cc < 96; cc++) {
        const int i = q * 768 + cc * 8;
        const unsigned short* xp;
        if (i < 1024) {
            xp = QLb + (size_t)row_g * DD + i;
        } else if (i < 2048) {
            const int j = i - 1024;
            xp = KCb + ((size_t)(b * HH + (j >> 6)) * LL + l) * 128 + 64 + (j & 63);
        } else {
            xp = TVLb + (size_t)row_g * DD + (i - 2048);
        }
        int4 xv = *(const int4*)xp;
        int4 wv = *(const int4*)(wp + cc * 8);
        const unsigned xs[4] = {(unsigned)xv.x, (unsigned)xv.y, (unsigned)xv.z, (unsigned)xv.w};
        const unsigned ws[4] = {(unsigned)wv.x, (unsigned)wv.y, (unsigned)wv.z, (unsigned)wv.w};
        #pragma unroll
        for (int jj = 0; jj < 4; jj++) {
            acc = fmaf(bflo(xs[jj]), bflo(ws[jj]), acc);
            acc = fmaf(bfhi(xs[jj]), bfhi(ws[jj]), acc);
        }
    }
    __shared__ float part[4][4][16];
    part[q][row][h] = acc;
    __syncthreads();
    if (t < 64) {
        float s = part[0][row][h] + part[1][row][h] + part[2][row][h] + part[3][row][h] + btw[h];
        GATE[(size_t)row_g * HH + h] = 1.f / (1.f + __expf(-s));
    }
}

// ---------------------------------------------------------------------------
// MFMA flash attention — r19: SWAPPED QK^T (T12): compute mfma(kf, qf) so each
// lane owns one full q-row (q = w*16+c) of 16 k-values. Softmax row-reduce
// becomes in-lane max tree + 2 shfl_xor (was 16 shfls), 1 mask-word load
// (was 4), 1 rescale exp2 (was 4), and P packs in-lane via cvt_pk into
// 4 ds_write_b64 (was 16 ds_write_b16 + 32 VALU). cf is transposed to the
// row-layout ctx/la via 4 width-16 __shfl. PV / la-ones / staging / epilogue
// are byte-identical to the round-10 body (r11 defer-max +7us; r12 setprio
// +20us; r16 (256,4) +3us — all still avoided).
// ---------------------------------------------------------------------------
__global__ __launch_bounds__(256, 3)
void attn_mfma(const unsigned short* __restrict__ QLb,
               const unsigned short* __restrict__ TVLb,
               const float* __restrict__ GATE,
               const unsigned short* __restrict__ KC,
               const unsigned short* __restrict__ VT,
               const unsigned long long* __restrict__ MB,
               unsigned short* __restrict__ CTb) {
    __shared__ char lds[32768];
    char* kc_l = lds;              // 16KB: 64 rows x 256B
    char* vt_l = lds + 16384;      // 8KB : 64 rows x 128B
    char* p_l  = lds + 24576;      // 8KB : wave w at +w*2048

    const int tid = threadIdx.x, w = tid >> 6, l = tid & 63;
    const int g = l >> 4, c = l & 15;
    const int flat = blockIdx.y * gridDim.x + blockIdx.x;
    const int wid = (flat & 7) * 128 + (flat >> 3);
    const int qb = wid & 15, bh = wid >> 4;
    const int b = bh >> 4, h = bh & 15;
    const int q0 = qb * 64;

    const size_t kcg = (size_t)bh * LL * 128;
    const size_t vtg = (size_t)bh * 64 * LL;

    const int kr = tid >> 4, ks = tid & 15;
    const size_t kgo = (size_t)kr * 128 + ks * 8;
    char* const klb = kc_l + kr * 256 + ((ks ^ (kr & 7)) << 4);
    const int vr = tid >> 3, vs = tid & 7;
    const size_t vgo = (size_t)vr * LL + vs * 8;
    char* const vlb = vt_l + vr * 128 + ((vs ^ (vr & 7)) << 4);

    int4 pk0, pk1, pk2, pk3, pv0, pv1;
    {
        const unsigned short* kp = KC + kcg + kgo;
        pk0 = *(const int4*)kp;
        pk1 = *(const int4*)(kp + 16 * 128);
        pk2 = *(const int4*)(kp + 32 * 128);
        pk3 = *(const int4*)(kp + 48 * 128);
        const unsigned short* vp = VT + vtg + vgo;
        pv0 = *(const int4*)vp;
        pv1 = *(const int4*)(vp + 32 * LL);
    }

    // ---- fused gate-folded Q' staging
    {
        const size_t rowbase = (size_t)b * LL + q0 + kr;
        const unsigned short* qsrc =
            (ks < 8 ? QLb : TVLb) + rowbase * DD + h * DHH + (ks & 7) * 8;
        const float* gp = GATE + rowbase * HH + h;
        #pragma unroll
        for (int i = 0; i < 4; i++) {
            const float p = gp[(size_t)i * 16 * HH];
            const float sc = (ks < 8 ? 1.f - p : p) * (0.125f * LOG2E);
            int4 v = *(const int4*)(qsrc + (size_t)i * 16 * DD);
            int4 o;
            o.x = cvt_pk_bf16(bflo((unsigned)v.x) * sc, bfhi((unsigned)v.x) * sc);
            o.y = cvt_pk_bf16(bflo((unsigned)v.y) * sc, bfhi((unsigned)v.y) * sc);
            o.z = cvt_pk_bf16(bflo((unsigned)v.z) * sc, bfhi((unsigned)v.z) * sc);
            o.w = cvt_pk_bf16(bflo((unsigned)v.w) * sc, bfhi((unsigned)v.w) * sc);
            *(int4*)(klb + i * 4096) = o;
        }
    }
    __syncthreads();
    s16x8 qf[4];
    const int ql = w * 16 + c;
    #pragma unroll
    for (int kss = 0; kss < 4; kss++) {
        int t = kss * 4 + g;
        qf[kss] = *(s16x8*)(kc_l + ql * 256 + ((t ^ (ql & 7)) << 4));
    }

    f32x4 ctx[4], la;
    #pragma unroll
    for (int ct = 0; ct < 4; ct++)
        #pragma unroll
        for (int j = 0; j < 4; j++) ctx[ct][j] = 0.f;
    #pragma unroll
    for (int j = 0; j < 4; j++) la[j] = 0.f;
    float m_s = -1e18f;   // running max for this lane's q-row (q = w*16+c)

    s16x8 ones;
    #pragma unroll
    for (int j = 0; j < 8; j++) ones[j] = (short)0x3F80;

    // per-lane mask-word pointer: row q = q0 + w*16 + c, one 64-bit word per kt
    const unsigned long long* mbq = MB + ((size_t)b * LL + q0 + w * 16 + c) * 16;

    for (int kt = 0; kt < 16; kt++) {
        __syncthreads();
        *(int4*)(klb)          = pk0;
        *(int4*)(klb + 4096)   = pk1;
        *(int4*)(klb + 8192)   = pk2;
        *(int4*)(klb + 12288)  = pk3;
        *(int4*)(vlb)          = pv0;
        *(int4*)(vlb + 4096)   = pv1;
        {
            const unsigned short* kp = KC + kcg + (size_t)(kt + 1) * (64 * 128) + kgo;
            pk0 = *(const int4*)kp;
            pk1 = *(const int4*)(kp + 16 * 128);
            pk2 = *(const int4*)(kp + 32 * 128);
            pk3 = *(const int4*)(kp + 48 * 128);
            const unsigned short* vp = VT + vtg + (size_t)(kt + 1) * 64 + vgo;
            pv0 = *(const int4*)vp;
            pv1 = *(const int4*)(vp + 32 * LL);
        }
        __syncthreads();

        // ---- swapped QK^T: sf[ct][j] = S[q = w*16+c][k = ct*16 + g*4 + j]
        f32x4 sf[4];
        #pragma unroll
        for (int ct = 0; ct < 4; ct++) {
            f32x4 acc;
            #pragma unroll
            for (int j = 0; j < 4; j++) acc[j] = 0.f;
            const int rk = ct * 16 + c;
            #pragma unroll
            for (int kss = 0; kss < 4; kss++) {
                int t = kss * 4 + g;
                s16x8 kf = *(s16x8*)(kc_l + rk * 256 + ((t ^ (rk & 7)) << 4));
                acc = __builtin_amdgcn_mfma_f32_16x16x32_bf16(kf, qf[kss], acc, 0, 0, 0);
            }
            sf[ct] = acc;
        }

        // ---- in-lane mask + row max (reduction axis k is lane-local now)
        {
            const unsigned long long mw = mbq[kt];
            const unsigned ms0 = (unsigned)(mw >> (g * 4));
            const unsigned ms1 = (unsigned)(mw >> (g * 4 + 32));
            #pragma unroll
            for (int ct = 0; ct < 4; ct++) {
                const unsigned mm = (ct & 2) ? ms1 : ms0;
                const int sh = (ct & 1) ? 16 : 0;
                #pragma unroll
                for (int j = 0; j < 4; j++)
                    if ((mm >> (sh + j)) & 1u) sf[ct][j] = -1e18f;
            }
            float t0 = fmaxf(fmaxf(sf[0][0], sf[0][1]), fmaxf(sf[0][2], sf[0][3]));
            float t1 = fmaxf(fmaxf(sf[1][0], sf[1][1]), fmaxf(sf[1][2], sf[1][3]));
            float t2 = fmaxf(fmaxf(sf[2][0], sf[2][1]), fmaxf(sf[2][2], sf[2][3]));
            float t3 = fmaxf(fmaxf(sf[3][0], sf[3][1]), fmaxf(sf[3][2], sf[3][3]));
            float mx = fmaxf(fmaxf(t0, t1), fmaxf(t2, t3));
            mx = fmaxf(mx, __shfl_xor(mx, 16));
            mx = fmaxf(mx, __shfl_xor(mx, 32));
            const float mn = fmaxf(m_s, mx);
            const float cf = exp2f(m_s - mn);
            m_s = mn;

            // transpose cf (lane layout q=c) -> row layout (q=g*4+r) for ctx/la
            const float cr0 = __shfl(cf, g * 4 + 0, 16);
            const float cr1 = __shfl(cf, g * 4 + 1, 16);
            const float cr2 = __shfl(cf, g * 4 + 2, 16);
            const float cr3 = __shfl(cf, g * 4 + 3, 16);
            #pragma unroll
            for (int ct = 0; ct < 4; ct++) {
                ctx[ct][0] *= cr0; ctx[ct][1] *= cr1;
                ctx[ct][2] *= cr2; ctx[ct][3] *= cr3;
            }
            la[0] *= cr0; la[1] *= cr1; la[2] *= cr2; la[3] *= cr3;

            // ---- P pack + store: lane's 4 k-contiguous values per ct -> b64
            char* pw = p_l + w * 2048 + c * 128;
            #pragma unroll
            for (int ct = 0; ct < 4; ct++) {
                const unsigned lo = cvt_pk_bf16(exp2f(sf[ct][0] - mn), exp2f(sf[ct][1] - mn));
                const unsigned hi = cvt_pk_bf16(exp2f(sf[ct][2] - mn), exp2f(sf[ct][3] - mn));
                const unsigned long long pkv =
                    (unsigned long long)lo | ((unsigned long long)hi << 32);
                *(unsigned long long*)(pw + (((ct * 2 + (g >> 1)) ^ (c & 7)) << 4) + ((g & 1) << 3)) = pkv;
            }
        }

        char* pb = p_l + w * 2048;
        s16x8 pa0 = *(s16x8*)(pb + c * 128 + (((0 + g) ^ (c & 7)) << 4));
        s16x8 pa1 = *(s16x8*)(pb + c * 128 + (((4 + g) ^ (c & 7)) << 4));
        #pragma unroll
        for (int ct = 0; ct < 4; ct++) {
            const int dv = ct * 16 + c;
            s16x8 v0 = *(s16x8*)(vt_l + dv * 128 + (((0 + g) ^ (dv & 7)) << 4));
            s16x8 v1 = *(s16x8*)(vt_l + dv * 128 + (((4 + g) ^ (dv & 7)) << 4));
            ctx[ct] = __builtin_amdgcn_mfma_f32_16x16x32_bf16(pa0, v0, ctx[ct], 0, 0, 0);
            ctx[ct] = __builtin_amdgcn_mfma_f32_16x16x32_bf16(pa1, v1, ctx[ct], 0, 0, 0);
        }
        la = __builtin_amdgcn_mfma_f32_16x16x32_bf16(pa0, ones, la, 0, 0, 0);
        la = __builtin_amdgcn_mfma_f32_16x16x32_bf16(pa1, ones, la, 0, 0, 0);
    }

    #pragma unroll
    for (int r = 0; r < 4; r++) {
        const float inv = 1.f / la[r];
        const int q = q0 + w * 16 + g * 4 + r;
        unsigned short* dst = CTb + ((size_t)b * LL + q) * DD + h * DHH + c;
        dst[0]  = f2bf(ctx[0][r] * inv);
        dst[16] = f2bf(ctx[1][r] * inv);
        dst[32] = f2bf(ctx[2][r] * inv);
        dst[48] = f2bf(ctx[3][r] * inv);
    }
}

// ---------------------------------------------------------------------------
extern "C" void kernel_launch(void* const* d_in, const int* in_sizes, int n_in,
                              void* d_out, int out_size, void* d_ws, size_t ws_size,
                              hipStream_t stream) {
    const float* key   = (const float*)d_in[0];
    const float* value = (const float*)d_in[1];
    const float* query = (const float*)d_in[2];
    const int*   mask  = (const int*)d_in[3];
    const float* topic = (const float*)d_in[4];
    const float* Wq  = (const float*)d_in[5];  const float* bq  = (const float*)d_in[6];
    const float* Wk  = (const float*)d_in[7];  const float* bk  = (const float*)d_in[8];
    const float* Wv  = (const float*)d_in[9];  const float* bv  = (const float*)d_in[10];
    const float* Wtk = (const float*)d_in[11]; const float* btk = (const float*)d_in[12];
    const float* Wtv = (const float*)d_in[13]; const float* btv = (const float*)d_in[14];
    const float* Wtw = (const float*)d_in[15]; const float* btw = (const float*)d_in[16];
    const float* Wo  = (const float*)d_in[17]; const float* bo  = (const float*)d_in[18];
    float* out = (float*)d_out;

    const size_t NTOK = (size_t)ML * DD;
    unsigned short* Wqb   = (unsigned short*)d_ws;                 // 5 x 1M (Wq,Wk,Wv,Wtk,Wo contiguous)
    unsigned short* Wkb   = Wqb  + (size_t)DD * DD;
    unsigned short* Wvb   = Wkb  + (size_t)DD * DD;
    unsigned short* Wtkb  = Wvb  + (size_t)DD * DD;
    unsigned short* Wob   = Wtkb + (size_t)DD * DD;
    unsigned short* Wtvb  = Wob  + (size_t)DD * DD;                // 1024*128
    unsigned short* Wtwb  = Wtvb + (size_t)DD * 128;               // 16*3072
    unsigned short* topicb= Wtwb + (size_t)HH * 3 * DD;            // 4096*128
    unsigned short* QLb   = topicb + (size_t)ML * 128;             // 4096*1024
    unsigned short* TVLb  = QLb  + NTOK;
    unsigned short* CTb   = TVLb + NTOK;
    unsigned short* KCb   = CTb  + NTOK;                           // 64*1024*128
    unsigned short* VTb   = KCb  + (size_t)BB * HH * LL * 128;     // 64*64*1024
    float* GATE           = (float*)(VTb + (size_t)BB * HH * 64 * LL);
    unsigned long long* MBp = (unsigned long long*)(GATE + (size_t)ML * HH);

    // ---- all converts + mask pack in one launch
    conv_fused<<<19288, 256, 0, stream>>>(Wq, Wk, Wv, Wtk, Wo, Wqb,
                                          Wtw, Wtwb, Wtv, Wtvb, topic, topicb,
                                          mask, MBp);

    // ---- fused projections: fp32 A, epilogue writes QLb / KC halves / VT
    gemm_mfma<1><<<dim3(DD / 128, ML / 128, 4), 256, 0, stream>>>(
        GArg{query, Wqb,  bq,  QLb, 1},
        GArg{key,   Wkb,  bk,  KCb, 2},
        GArg{value, Wvb,  bv,  VTb, 4},
        GArg{key,   Wtkb, btk, KCb, 3},
        DD, DD);
    // ---- topic-query GEMM (bf16 A, K padded to 128) -> TVLb bf16
    gemm_mfma<0><<<dim3(DD / 128, ML / 128, 1), 256, 0, stream>>>(
        GArg{topicb, Wtvb, btv, TVLb, 1},
        GArg{topicb, Wtvb, btv, TVLb, 1},
        GArg{topicb, Wtvb, btv, TVLb, 1},
        GArg{topicb, Wtvb, btv, TVLb, 1},
        DD, 128);

    gate_kernel<<<ML / 4, 256, 0, stream>>>(QLb, KCb, TVLb, Wtwb, btw, GATE);

    attn_mfma<<<dim3(LL / 64, BB * HH), 256, 0, stream>>>(QLb, TVLb, GATE, KCb, VTb, MBp, CTb);

    // ---- output projection (bf16 A)
    gemm_mfma<0><<<dim3(DD / 128, ML / 128, 1), 256, 0, stream>>>(
        GArg{CTb, Wob, bo, out, 0},
        GArg{CTb, Wob, bo, out, 0},
        GArg{CTb, Wob, bo, out, 0},
        GArg{CTb, Wob, bo, out, 0},
        DD, DD);
}